// Round 5
// baseline (151.288 us; speedup 1.0000x reference)
//
#include <hip/hip_runtime.h>

#define B_ 32
#define C_ 80
#define T_ 2048
#define W_ 128
#define H_ 512
#define K_ 5

#define KTOT 400          // C_*K_
#define KPAD 416          // padded to 13*32
#define NKI  13           // K iterations of 32
#define TM   128
#define TN   128
#define SF_STRIDE 88      // f16 units
#define SF_ROWS   136     // 128 + 4 halo + 4 tail-slack
#define BF_ELEMS  (4 * NKI * 2 * 4 * 64 * 8)   // [nt][it][w2][j][lane][8] = 212992

// prep_all block-role boundaries
#define RB_FEAT   1024    // convert_feat blocks
#define RB_BFRAG  (RB_FEAT + BF_ELEMS / 256)   // 1024 + 832 = 1856
#define RB_WORDS  (RB_BFRAG + B_)              // 1888
#define RB_OUT    (RB_WORDS + (B_ * W_) / 256) // 1904

typedef _Float16 half8 __attribute__((ext_vector_type(8)));
typedef float    f4v   __attribute__((ext_vector_type(4)));

// ---------------------------------------------------------------------------
// prep_all: one dispatch, four roles by blockIdx.x:
//  [0,1024)      feat (B,C,T) fp32 -> featT (B,T,C) f16 (LDS tile-transpose)
//  [1024,1856)   enc_w -> Bf wave-fragment order (see gemm for layout)
//  [1856,1888)   word_of inverse map + inv_cnt (block per b)
//  [1888,1904)   out[b,w] = dec_b  (decoder bias init; gemm atomically adds)
// ---------------------------------------------------------------------------
__global__ __launch_bounds__(256) void prep_all(
    const float* __restrict__ feat, const float* __restrict__ enc_w,
    const int* __restrict__ bounds, const int* __restrict__ lengths,
    const float* __restrict__ dec_b,
    _Float16* __restrict__ featT, _Float16* __restrict__ Bf,
    int* __restrict__ word_of, float* __restrict__ inv_cnt,
    float* __restrict__ out)
{
    __shared__ _Float16 tile[64 * 80];
    const int bid = blockIdx.x;
    const int tid = threadIdx.x;

    if (bid < RB_FEAT) {
        const int b = bid >> 5, tc = bid & 31;
        const int t0 = tc * 64;
        for (int idx = tid; idx < 80 * 64; idx += 256) {
            int cc = idx >> 6, tt = idx & 63;                  // coalesced over tt
            float v = feat[((size_t)b * C_ + cc) * T_ + t0 + tt];
            tile[tt * 80 + cc] = (_Float16)v;
        }
        __syncthreads();
        for (int idx = tid; idx < 64 * 10; idx += 256) {
            int tt = idx / 10, g = idx % 10;                   // coalesced writes
            *(f4v*)(featT + ((size_t)b * T_ + t0 + tt) * C_ + g * 8) =
                *(const f4v*)(tile + tt * 80 + g * 8);
        }
    } else if (bid < RB_BFRAG) {
        int idx = (bid - RB_FEAT) * 256 + tid;                 // < BF_ELEMS exactly
        int e  = idx & 7;
        int l  = (idx >> 3) & 63;
        int j  = (idx >> 9) & 3;
        int w2 = (idx >> 11) & 1;
        int it = (idx >> 12) % NKI;
        int nt = idx / (NKI << 12);
        int h  = nt * 128 + w2 * 64 + j * 16 + (l & 15);
        int kc = it * 32 + (l >> 4) * 8 + e;
        float v = 0.f;
        if (kc < KTOT) v = enc_w[(h * C_ + kc % 80) * K_ + kc / 80];
        Bf[idx] = (_Float16)v;
    } else if (bid < RB_WORDS) {
        const int b = bid - RB_BFRAG;
        int* wob = word_of + b * T_;
        for (int t = tid; t < T_; t += 256) wob[t] = -1;
        __syncthreads();
        if (tid < W_) {
            const int len = lengths[b];
            int s = bounds[(b * 2 + 0) * W_ + tid];
            int e = bounds[(b * 2 + 1) * W_ + tid];
            s = max(s, 0); e = min(e, T_);
            bool valid = (tid < len) && (e > s);
            inv_cnt[b * W_ + tid] = valid ? 1.f / (float)(e - s) : 0.f;
            if (valid)
                for (int t = s; t < e; ++t) wob[t] = tid;      // disjoint words
        }
    } else {
        int idx = (bid - RB_WORDS) * 256 + tid;
        if (idx < B_ * W_) out[idx] = dec_b[0];
    }
}

// ---------------------------------------------------------------------------
// Implicit-GEMM conv (f16 MFMA) + bias + ReLU + word mean-pool + DECODER,
// all fused. A staged once in LDS; B fragments streamed L2-hot in wave order
// (barrier-free K-loop). Decoder is linear in wemb, so each pooled value
// val(w0,h) adds val*dec_w[h,k] into out[b, w0+2-k] via block-local eloc[]
// then one guarded global atomicAdd flush.
// ---------------------------------------------------------------------------
__global__ __launch_bounds__(256) void gemm_enc_fused(
    const _Float16* __restrict__ featT,   // (B,T,C)
    const _Float16* __restrict__ Bf,      // wave-order fragments
    const float*    __restrict__ enc_b,   // (H)
    const int*      __restrict__ word_of, // (B,T)
    const float*    __restrict__ inv_cnt, // (B,W)
    const float*    __restrict__ dec_w,   // (1,H,K) flat h*K+k
    float*          __restrict__ out)     // (B,W), pre-set to dec_b
{
    __shared__ _Float16 sf[SF_ROWS * SF_STRIDE];   // 23.9 KB
    __shared__ float    sdw[TN * K_];              // 2.5 KB: dec_w slice for h0..h0+127
    __shared__ float    eloc[W_ + 4];              // 528 B: out partials, idx = w' + 2

    const int tid = threadIdx.x;
    const int bid = blockIdx.x;
    const int nt = bid & 3;
    const int mt = (bid >> 2) & 15;
    const int b  = bid >> 6;
    const int t0 = mt * TM;
    const int h0 = nt * TN;

    // ---- pre-barrier staging: A tile, dec_w slice, eloc zeros ----
    const _Float16* fb = featT + (size_t)b * T_ * C_;
    for (int idx = tid; idx < SF_ROWS * 10; idx += 256) {
        int tt = idx / 10, g = idx % 10;
        int t = t0 - 2 + tt;
        int tcl = min(max(t, 0), T_ - 1);
        f4v v = {};
        if (t >= 0 && t < T_) v = *(const f4v*)(fb + tcl * C_ + g * 8);
        *(f4v*)(sf + tt * SF_STRIDE + g * 8) = v;
    }
    for (int idx = tid; idx < TN * K_; idx += 256) sdw[idx] = dec_w[h0 * K_ + idx];
    if (tid < W_ + 4) eloc[tid] = 0.f;

    const int lane = tid & 63;
    const int wid  = tid >> 6;
    const int wm = (wid >> 1) * 64;
    const int wn = (wid & 1) * 64;
    const int w2 = wid & 1;
    const int ml = lane & 15;
    const int q  = lane >> 4;

    const half8* bfp = (const half8*)(Bf + (((nt * NKI) * 2 + w2) * 4 * 64 + lane) * 8);

    f4v acc[4][4] = {};

    __syncthreads();   // sf/sdw/eloc ready; no more barriers until flush

    int c = q * 8;
    int aoff = (wm + ml) * SF_STRIDE + c;

    half8 bcur[4];
    #pragma unroll
    for (int j = 0; j < 4; ++j) bcur[j] = bfp[j * 64];

    for (int it = 0; it < NKI; ++it) {
        half8 bnext[4];
        if (it + 1 < NKI) {
            const half8* bn = bfp + (it + 1) * (2 * 4 * 64);
            #pragma unroll
            for (int j = 0; j < 4; ++j) bnext[j] = bn[j * 64];
        }
        half8 af[4];
        #pragma unroll
        for (int i = 0; i < 4; ++i)
            af[i] = *(const half8*)(sf + aoff + i * 16 * SF_STRIDE);
        #pragma unroll
        for (int i = 0; i < 4; ++i)
            #pragma unroll
            for (int j = 0; j < 4; ++j)
                acc[i][j] = __builtin_amdgcn_mfma_f32_16x16x32_f16(af[i], bcur[j], acc[i][j], 0, 0, 0);
        #pragma unroll
        for (int j = 0; j < 4; ++j) bcur[j] = bnext[j];
        aoff += 32; c += 32;
        if (c >= 80) { c -= 80; aoff += 8; }
    }

    // ---- epilogue: bias + ReLU + mean-pool + decoder transform ----
    const int bT = b * T_;
    const int bW = b * W_;
    float bias[4];
    #pragma unroll
    for (int j = 0; j < 4; ++j) bias[j] = enc_b[h0 + wn + j * 16 + ml];

    #pragma unroll
    for (int i = 0; i < 4; ++i) {
        const int tg = t0 + wm + i * 16;
        const int w0  = word_of[bT + tg];
        const int w15 = word_of[bT + tg + 15];
        if (w0 == w15) {
            if (w0 >= 0) {
                const float inv = inv_cnt[bW + w0];
                #pragma unroll
                for (int j = 0; j < 4; ++j) {
                    float s = 0.f;
                    #pragma unroll
                    for (int r = 0; r < 4; ++r) s += fmaxf(acc[i][j][r] + bias[j], 0.f);
                    s += __shfl_down(s, 32, 64);   // fold q=2,3 into q=0,1
                    s += __shfl_down(s, 16, 64);   // fold q=1 into q=0
                    if (q == 0) {
                        const float val = s * inv;           // pooled wemb value
                        const int hl = (wn + j * 16 + ml) * K_;
                        #pragma unroll
                        for (int k = 0; k < K_; ++k) {
                            float p = val * sdw[hl + k];
                            p += __shfl_xor(p, 1, 64);       // reduce over 16 h-lanes
                            p += __shfl_xor(p, 2, 64);
                            p += __shfl_xor(p, 4, 64);
                            p += __shfl_xor(p, 8, 64);
                            if (ml == 0) atomicAdd(&eloc[w0 + 4 - k], p);  // w'=w0+2-k
                        }
                    }
                }
            }
        } else {   // general path: frames in this group belong to different words
            #pragma unroll
            for (int j = 0; j < 4; ++j) {
                const int hl = (wn + j * 16 + ml) * K_;
                #pragma unroll
                for (int r = 0; r < 4; ++r) {
                    int t = tg + q * 4 + r;
                    int w = word_of[bT + t];
                    if (w >= 0) {
                        float val = fmaxf(acc[i][j][r] + bias[j], 0.f) * inv_cnt[bW + w];
                        #pragma unroll
                        for (int k = 0; k < K_; ++k)
                            atomicAdd(&eloc[w + 4 - k], val * sdw[hl + k]);
                    }
                }
            }
        }
    }

    __syncthreads();
    for (int idx = tid; idx < W_ + 4; idx += 256) {
        float v = eloc[idx];
        int w = idx - 2;
        if (v != 0.f && w >= 0 && w < W_) atomicAdd(&out[bW + w], v);
    }
}

// ---------------------------------------------------------------------------
extern "C" void kernel_launch(void* const* d_in, const int* in_sizes, int n_in,
                              void* d_out, int out_size, void* d_ws, size_t ws_size,
                              hipStream_t stream) {
    const float* feat    = (const float*)d_in[0];
    const int*   bounds  = (const int*)  d_in[1];
    const int*   lengths = (const int*)  d_in[2];
    const float* enc_w   = (const float*)d_in[3];
    const float* enc_b   = (const float*)d_in[4];
    const float* dec_w   = (const float*)d_in[5];
    const float* dec_b   = (const float*)d_in[6];
    float* out = (float*)d_out;

    char* p = (char*)d_ws;
    _Float16* featT = (_Float16*)p;  p += (size_t)B_ * T_ * C_ * 2;       // 10.49 MB
    _Float16* Bf    = (_Float16*)p;  p += (size_t)BF_ELEMS * 2;           // 0.43 MB
    int* word_of    = (int*)p;       p += (size_t)B_ * T_ * 4;            // 0.26 MB
    float* inv_cnt  = (float*)p;                                          // 16 KB

    prep_all<<<RB_OUT, 256, 0, stream>>>(feat, enc_w, bounds, lengths, dec_b,
                                         featT, Bf, word_of, inv_cnt, out);
    gemm_enc_fused<<<B_ * (T_ / TM) * (H_ / TN), 256, 0, stream>>>(
        featT, Bf, enc_b, word_of, inv_cnt, dec_w, out);
}

// Round 6
// 130.019 us; speedup vs baseline: 1.1636x; 1.1636x over previous
//
#include <hip/hip_runtime.h>

#define B_ 32
#define C_ 80
#define T_ 2048
#define W_ 128
#define H_ 512
#define K_ 5

#define KTOT 400          // C_*K_
#define KPAD 416          // padded to 13*32
#define NKI  13           // K iterations of 32
#define TM   128
#define TN   128
#define SF_STRIDE 88      // f16 units
#define SF_ROWS   136     // 128 + 4 halo + 4 tail-slack
#define ITER_STRIDE (2 * 4 * 64 * 8)               // Bf elems per K-iter per nt
#define BF_ELEMS  (4 * NKI * ITER_STRIDE)          // [nt][it][w2][j][lane][8] = 212992

// prep_all block-role boundaries
#define RB_FEAT   1024                             // feat transpose blocks
#define RB_BFRAG  (RB_FEAT + BF_ELEMS / 256)       // +832 = 1856
#define RB_WORDS  (RB_BFRAG + B_)                  // +32  = 1888
#define RB_WZERO  (RB_WORDS + 128)                 // +128 = 2016 (wemb zero)

typedef _Float16 half8 __attribute__((ext_vector_type(8)));
typedef float    f4v   __attribute__((ext_vector_type(4)));

// ---------------------------------------------------------------------------
// prep_all: one dispatch, four roles by blockIdx.x:
//  [0,1024)      feat (B,C,T) fp32 -> featT (B,T,C) f16 (LDS tile-transpose)
//  [1024,1856)   enc_w -> Bf wave-fragment order (layout in gemm_enc)
//  [1856,1888)   word_of inverse map + inv_cnt (block per b)
//  [1888,2016)   wemb = 0  (fast-path plain stores + atomic boundary path)
// ---------------------------------------------------------------------------
__global__ __launch_bounds__(256) void prep_all(
    const float* __restrict__ feat, const float* __restrict__ enc_w,
    const int* __restrict__ bounds, const int* __restrict__ lengths,
    _Float16* __restrict__ featT, _Float16* __restrict__ Bf,
    int* __restrict__ word_of, float* __restrict__ inv_cnt,
    float* __restrict__ wemb)
{
    __shared__ _Float16 tile[64 * 80];
    const int bid = blockIdx.x;
    const int tid = threadIdx.x;

    if (bid < RB_FEAT) {
        const int b = bid >> 5, tc = bid & 31;
        const int t0 = tc * 64;
        for (int idx = tid; idx < 80 * 64; idx += 256) {
            int cc = idx >> 6, tt = idx & 63;                  // coalesced over tt
            float v = feat[((size_t)b * C_ + cc) * T_ + t0 + tt];
            tile[tt * 80 + cc] = (_Float16)v;
        }
        __syncthreads();
        for (int idx = tid; idx < 64 * 10; idx += 256) {
            int tt = idx / 10, g = idx % 10;                   // coalesced writes
            *(f4v*)(featT + ((size_t)b * T_ + t0 + tt) * C_ + g * 8) =
                *(const f4v*)(tile + tt * 80 + g * 8);
        }
    } else if (bid < RB_BFRAG) {
        int idx = (bid - RB_FEAT) * 256 + tid;                 // < BF_ELEMS exactly
        int e  = idx & 7;
        int l  = (idx >> 3) & 63;
        int j  = (idx >> 9) & 3;
        int w2 = (idx >> 11) & 1;
        int it = (idx >> 12) % NKI;
        int nt = idx / (NKI << 12);
        int h  = nt * 128 + w2 * 64 + j * 16 + (l & 15);
        int kc = it * 32 + (l >> 4) * 8 + e;
        float v = 0.f;
        if (kc < KTOT) v = enc_w[(h * C_ + kc % 80) * K_ + kc / 80];
        Bf[idx] = (_Float16)v;
    } else if (bid < RB_WORDS) {
        const int b = bid - RB_BFRAG;
        int* wob = word_of + b * T_;
        for (int t = tid; t < T_; t += 256) wob[t] = -1;
        __syncthreads();
        if (tid < W_) {
            const int len = lengths[b];
            int s = bounds[(b * 2 + 0) * W_ + tid];
            int e = bounds[(b * 2 + 1) * W_ + tid];
            s = max(s, 0); e = min(e, T_);
            bool valid = (tid < len) && (e > s);
            inv_cnt[b * W_ + tid] = valid ? 1.f / (float)(e - s) : 0.f;
            if (valid)
                for (int t = s; t < e; ++t) wob[t] = tid;      // disjoint words
        }
    } else {
        // zero wemb: B*W*H floats = 524288 f4v over 128 blocks
        f4v* wz = (f4v*)wemb;
        int base = (bid - RB_WORDS) * 256 + tid;
        for (int i = base; i < (B_ * W_ * H_) / 4; i += 128 * 256) wz[i] = (f4v){};
    }
}

// ---------------------------------------------------------------------------
// Implicit-GEMM conv (f16 MFMA) + bias + ReLU + word mean-pool into wemb.
// A staged once in LDS; B fragments streamed L2-hot in wave order
// (barrier-free, branchless K-loop; Bf padded one iter so prefetch never
// branches). Epilogue: plain store when the 16-frame group solely owns its
// word, else atomics.
// ---------------------------------------------------------------------------
__global__ __launch_bounds__(256, 3) void gemm_enc(
    const _Float16* __restrict__ featT,   // (B,T,C)
    const _Float16* __restrict__ Bf,      // wave-order fragments (padded +1 iter)
    const float*    __restrict__ enc_b,   // (H)
    const int*      __restrict__ word_of, // (B,T)
    const float*    __restrict__ inv_cnt, // (B,W)
    float*          __restrict__ wemb)    // (B,W,H) pre-zeroed
{
    __shared__ _Float16 sf[SF_ROWS * SF_STRIDE];   // 23.9 KB

    const int tid = threadIdx.x;
    const int bid = blockIdx.x;
    const int nt = bid & 3;          // nt in low bits: same-nt blocks share an XCD
    const int mt = (bid >> 2) & 15;  //   under round-robin bid->XCD (L2 Bf reuse)
    const int b  = bid >> 6;
    const int t0 = mt * TM;
    const int h0 = nt * TN;

    // ---- stage A tile (rows tt: t = t0-2+tt, zero outside [0,T)) ----
    const _Float16* fb = featT + (size_t)b * T_ * C_;
    for (int idx = tid; idx < SF_ROWS * 10; idx += 256) {
        int tt = idx / 10, g = idx % 10;
        int t = t0 - 2 + tt;
        int tcl = min(max(t, 0), T_ - 1);
        f4v v = {};
        if (t >= 0 && t < T_) v = *(const f4v*)(fb + tcl * C_ + g * 8);
        *(f4v*)(sf + tt * SF_STRIDE + g * 8) = v;
    }

    const int lane = tid & 63;
    const int wid  = tid >> 6;
    const int wm = (wid >> 1) * 64;
    const int wn = (wid & 1) * 64;
    const int w2 = wid & 1;
    const int ml = lane & 15;
    const int q  = lane >> 4;

    const half8* bfp = (const half8*)(Bf + (((nt * NKI) * 2 + w2) * 4 * 64 + lane) * 8);

    f4v acc[4][4] = {};

    __syncthreads();   // sf ready; no more barriers below

    int c = q * 8;
    int aoff = (wm + ml) * SF_STRIDE + c;

    half8 bcur[4];
    #pragma unroll
    for (int j = 0; j < 4; ++j) bcur[j] = bfp[j * 64];

    for (int it = 0; it < NKI; ++it) {
        half8 bnext[4];
        {   // branchless: it=12 prefetches padded garbage, never consumed
            const half8* bn = bfp + (it + 1) * (2 * 4 * 64);
            #pragma unroll
            for (int j = 0; j < 4; ++j) bnext[j] = bn[j * 64];
        }
        half8 af[4];
        #pragma unroll
        for (int i = 0; i < 4; ++i)
            af[i] = *(const half8*)(sf + aoff + i * 16 * SF_STRIDE);
        #pragma unroll
        for (int i = 0; i < 4; ++i)
            #pragma unroll
            for (int j = 0; j < 4; ++j)
                acc[i][j] = __builtin_amdgcn_mfma_f32_16x16x32_f16(af[i], bcur[j], acc[i][j], 0, 0, 0);
        #pragma unroll
        for (int j = 0; j < 4; ++j) bcur[j] = bnext[j];
        aoff += 32; c += 32;
        if (c >= 80) { c -= 80; aoff += 8; }
    }

    // ---- epilogue: bias + ReLU + mean-pool ----
    const int bT = b * T_;
    const int bW = b * W_;
    float bias[4];
    #pragma unroll
    for (int j = 0; j < 4; ++j) bias[j] = enc_b[h0 + wn + j * 16 + ml];

    #pragma unroll
    for (int i = 0; i < 4; ++i) {
        const int tg = t0 + wm + i * 16;
        const int w0  = word_of[bT + tg];
        const int w15 = word_of[bT + tg + 15];
        if (w0 == w15) {
            if (w0 >= 0) {
                const float inv = inv_cnt[bW + w0];
                const bool own_lo = (tg == 0) || (word_of[bT + tg - 1] != w0);
                const bool own_hi = (tg + 16 >= T_) || (word_of[bT + tg + 16] != w0);
                #pragma unroll
                for (int j = 0; j < 4; ++j) {
                    float s = 0.f;
                    #pragma unroll
                    for (int r = 0; r < 4; ++r) s += fmaxf(acc[i][j][r] + bias[j], 0.f);
                    s += __shfl_down(s, 32, 64);
                    s += __shfl_down(s, 16, 64);
                    if (q == 0) {
                        float val = s * inv;
                        float* dst = &wemb[(size_t)(bW + w0) * H_ + h0 + wn + j * 16 + ml];
                        if (own_lo && own_hi) *dst = val;       // sole owner
                        else atomicAdd(dst, val);
                    }
                }
            }
        } else {
            #pragma unroll
            for (int j = 0; j < 4; ++j) {
                #pragma unroll
                for (int r = 0; r < 4; ++r) {
                    int t = tg + q * 4 + r;
                    int w = word_of[bT + t];
                    if (w >= 0)
                        atomicAdd(&wemb[(size_t)(bW + w) * H_ + h0 + wn + j * 16 + ml],
                                  fmaxf(acc[i][j][r] + bias[j], 0.f) * inv_cnt[bW + w]);
                }
            }
        }
    }
}

// ---------------------------------------------------------------------------
// Decoder, single dispatch: block = (b, 32-word chunk). Computes the 36
// needed e[w',k] = sum_h wemb[b,w',h]*dec_w[h,k] rows (incl. 2-halo each
// side, recomputed) into LDS, then combines: out = dec_b + sum_k e[w+k-2][k].
// ---------------------------------------------------------------------------
__global__ __launch_bounds__(256) void dec_all(const float* __restrict__ wemb,
                                               const float* __restrict__ dec_w,
                                               const float* __restrict__ dec_b,
                                               float* __restrict__ out) {
    __shared__ float sdw[H_ * K_];       // 10.2 KB
    __shared__ float se[36][8];          // e rows, k-stride 8
    const int bid = blockIdx.x;          // b*4 + ch
    const int b = bid >> 2, ch = bid & 3;
    const int w0 = ch * 32;
    for (int idx = threadIdx.x; idx < H_ * K_; idx += 256) sdw[idx] = dec_w[idx];
    __syncthreads();
    const int wid = threadIdx.x >> 6, lane = threadIdx.x & 63;
    for (int row = wid; row < 36; row += 4) {
        int wq = w0 - 2 + row;
        float a[K_] = {};
        if (wq >= 0 && wq < W_) {
            const float* src = wemb + ((size_t)b * W_ + wq) * H_;
            #pragma unroll
            for (int r = 0; r < H_ / 64; ++r) {
                int h = r * 64 + lane;
                float v = src[h];
                #pragma unroll
                for (int k = 0; k < K_; ++k) a[k] += v * sdw[h * K_ + k];
            }
        }
        #pragma unroll
        for (int k = 0; k < K_; ++k) {
            #pragma unroll
            for (int off = 32; off > 0; off >>= 1) a[k] += __shfl_down(a[k], off, 64);
        }
        if (lane == 0) {
            #pragma unroll
            for (int k = 0; k < K_; ++k) se[row][k] = a[k];
        }
    }
    __syncthreads();
    if (threadIdx.x < 32) {
        int wl = threadIdx.x;
        float acc = dec_b[0];
        #pragma unroll
        for (int k = 0; k < K_; ++k) acc += se[wl + k][k];
        out[b * W_ + w0 + wl] = acc;
    }
}

// ---------------------------------------------------------------------------
extern "C" void kernel_launch(void* const* d_in, const int* in_sizes, int n_in,
                              void* d_out, int out_size, void* d_ws, size_t ws_size,
                              hipStream_t stream) {
    const float* feat    = (const float*)d_in[0];
    const int*   bounds  = (const int*)  d_in[1];
    const int*   lengths = (const int*)  d_in[2];
    const float* enc_w   = (const float*)d_in[3];
    const float* enc_b   = (const float*)d_in[4];
    const float* dec_w   = (const float*)d_in[5];
    const float* dec_b   = (const float*)d_in[6];
    float* out = (float*)d_out;

    char* p = (char*)d_ws;
    _Float16* featT = (_Float16*)p;  p += (size_t)B_ * T_ * C_ * 2;           // 10.49 MB
    _Float16* Bf    = (_Float16*)p;  p += (size_t)(BF_ELEMS + ITER_STRIDE) * 2; // 0.43 MB (+pad)
    int* word_of    = (int*)p;       p += (size_t)B_ * T_ * 4;                // 0.26 MB
    float* inv_cnt  = (float*)p;     p += (size_t)B_ * W_ * 4;                // 16 KB
    float* wemb     = (float*)p;                                              // 8.39 MB

    prep_all<<<RB_WZERO, 256, 0, stream>>>(feat, enc_w, bounds, lengths,
                                           featT, Bf, word_of, inv_cnt, wemb);
    gemm_enc<<<B_ * (T_ / TM) * (H_ / TN), 256, 0, stream>>>(
        featT, Bf, enc_b, word_of, inv_cnt, wemb);
    dec_all<<<B_ * 4, 256, 0, stream>>>(wemb, dec_w, dec_b, out);
}

// Round 7
// 129.711 us; speedup vs baseline: 1.1663x; 1.0024x over previous
//
#include <hip/hip_runtime.h>

#define B_ 32
#define C_ 80
#define T_ 2048
#define W_ 128
#define H_ 512
#define K_ 5

#define KTOT 400          // C_*K_
#define KPAD 416          // padded to 13*32
#define NKI  13           // K iterations of 32
#define TM   128
#define TN   128
#define SF_STRIDE 88      // f16 units
#define SF_ROWS   136     // 128 + 4 halo + 4 tail-slack (A-prefetch overrun safe)
#define ITER_STRIDE (2 * 4 * 64 * 8)               // Bf elems per K-iter per nt
#define BF_ELEMS  (4 * NKI * ITER_STRIDE)          // [nt][it][w2][j][lane][8] = 212992

// prep_all block-role boundaries
#define RB_FEAT   1024                             // feat transpose blocks
#define RB_BFRAG  (RB_FEAT + BF_ELEMS / 256)       // +832 = 1856
#define RB_WORDS  (RB_BFRAG + B_)                  // +32  = 1888
#define RB_WZERO  (RB_WORDS + 128)                 // +128 = 2016 (wemb zero)

typedef _Float16 half8 __attribute__((ext_vector_type(8)));
typedef float    f4v   __attribute__((ext_vector_type(4)));

// ---------------------------------------------------------------------------
// prep_all: one dispatch, four roles by blockIdx.x (unchanged from round 6)
// ---------------------------------------------------------------------------
__global__ __launch_bounds__(256) void prep_all(
    const float* __restrict__ feat, const float* __restrict__ enc_w,
    const int* __restrict__ bounds, const int* __restrict__ lengths,
    _Float16* __restrict__ featT, _Float16* __restrict__ Bf,
    int* __restrict__ word_of, float* __restrict__ inv_cnt,
    float* __restrict__ wemb)
{
    __shared__ _Float16 tile[64 * 80];
    const int bid = blockIdx.x;
    const int tid = threadIdx.x;

    if (bid < RB_FEAT) {
        const int b = bid >> 5, tc = bid & 31;
        const int t0 = tc * 64;
        for (int idx = tid; idx < 80 * 64; idx += 256) {
            int cc = idx >> 6, tt = idx & 63;                  // coalesced over tt
            float v = feat[((size_t)b * C_ + cc) * T_ + t0 + tt];
            tile[tt * 80 + cc] = (_Float16)v;
        }
        __syncthreads();
        for (int idx = tid; idx < 64 * 10; idx += 256) {
            int tt = idx / 10, g = idx % 10;                   // coalesced writes
            *(f4v*)(featT + ((size_t)b * T_ + t0 + tt) * C_ + g * 8) =
                *(const f4v*)(tile + tt * 80 + g * 8);
        }
    } else if (bid < RB_BFRAG) {
        int idx = (bid - RB_FEAT) * 256 + tid;                 // < BF_ELEMS exactly
        int e  = idx & 7;
        int l  = (idx >> 3) & 63;
        int j  = (idx >> 9) & 3;
        int w2 = (idx >> 11) & 1;
        int it = (idx >> 12) % NKI;
        int nt = idx / (NKI << 12);
        int h  = nt * 128 + w2 * 64 + j * 16 + (l & 15);
        int kc = it * 32 + (l >> 4) * 8 + e;
        float v = 0.f;
        if (kc < KTOT) v = enc_w[(h * C_ + kc % 80) * K_ + kc / 80];
        Bf[idx] = (_Float16)v;
    } else if (bid < RB_WORDS) {
        const int b = bid - RB_BFRAG;
        int* wob = word_of + b * T_;
        for (int t = tid; t < T_; t += 256) wob[t] = -1;
        __syncthreads();
        if (tid < W_) {
            const int len = lengths[b];
            int s = bounds[(b * 2 + 0) * W_ + tid];
            int e = bounds[(b * 2 + 1) * W_ + tid];
            s = max(s, 0); e = min(e, T_);
            bool valid = (tid < len) && (e > s);
            inv_cnt[b * W_ + tid] = valid ? 1.f / (float)(e - s) : 0.f;
            if (valid)
                for (int t = s; t < e; ++t) wob[t] = tid;      // disjoint words
        }
    } else {
        f4v* wz = (f4v*)wemb;
        int base = (bid - RB_WORDS) * 256 + tid;
        for (int i = base; i < (B_ * W_ * H_) / 4; i += 128 * 256) wz[i] = (f4v){};
    }
}

// ---------------------------------------------------------------------------
// Implicit-GEMM conv (f16 MFMA) + bias + ReLU + word mean-pool into wemb.
// Round-7 change: register double-buffer for A fragments (ds_read for it+1
// issued before MFMAs of it, hiding LDS latency), epilogue word_of scalars
// prefetched before the K-loop, occupancy request bumped to 4 waves/EU.
// ---------------------------------------------------------------------------
__global__ __launch_bounds__(256, 4) void gemm_enc(
    const _Float16* __restrict__ featT,   // (B,T,C)
    const _Float16* __restrict__ Bf,      // wave-order fragments (padded +1 iter)
    const float*    __restrict__ enc_b,   // (H)
    const int*      __restrict__ word_of, // (B,T)
    const float*    __restrict__ inv_cnt, // (B,W)
    float*          __restrict__ wemb)    // (B,W,H) pre-zeroed
{
    __shared__ _Float16 sf[SF_ROWS * SF_STRIDE];   // 23.9 KB

    const int tid = threadIdx.x;
    const int bid = blockIdx.x;
    const int nt = bid & 3;          // nt in low bits: Bf slice L2 locality
    const int mt = (bid >> 2) & 15;
    const int b  = bid >> 6;
    const int t0 = mt * TM;
    const int h0 = nt * TN;

    // ---- stage A tile (rows tt: t = t0-2+tt, zero outside [0,T)) ----
    const _Float16* fb = featT + (size_t)b * T_ * C_;
    for (int idx = tid; idx < SF_ROWS * 10; idx += 256) {
        int tt = idx / 10, g = idx % 10;
        int t = t0 - 2 + tt;
        int tcl = min(max(t, 0), T_ - 1);
        f4v v = {};
        if (t >= 0 && t < T_) v = *(const f4v*)(fb + tcl * C_ + g * 8);
        *(f4v*)(sf + tt * SF_STRIDE + g * 8) = v;
    }

    const int lane = tid & 63;
    const int wid  = tid >> 6;
    const int wm = (wid >> 1) * 64;
    const int wn = (wid & 1) * 64;
    const int w2 = wid & 1;
    const int ml = lane & 15;
    const int q  = lane >> 4;

    const half8* bfp = (const half8*)(Bf + (((nt * NKI) * 2 + w2) * 4 * 64 + lane) * 8);

    // ---- epilogue scalar prefetch (independent of K-loop) ----
    const int bT = b * T_;
    const int bW = b * W_;
    int wlo[4], whi[4];
    #pragma unroll
    for (int i = 0; i < 4; ++i) {
        const int tg = t0 + wm + i * 16;
        wlo[i] = word_of[bT + tg];
        whi[i] = word_of[bT + tg + 15];
    }

    f4v acc[4][4] = {};

    __syncthreads();   // sf ready; no more barriers below

    int c = q * 8;
    int aoff = (wm + ml) * SF_STRIDE + c;

    // preload iter 0 fragments (A from LDS, B from global)
    half8 acur[4], bcur[4];
    #pragma unroll
    for (int i = 0; i < 4; ++i)
        acur[i] = *(const half8*)(sf + aoff + i * 16 * SF_STRIDE);
    #pragma unroll
    for (int j = 0; j < 4; ++j) bcur[j] = bfp[j * 64];
    aoff += 32; c += 32;
    if (c >= 80) { c -= 80; aoff += 8; }

    for (int it = 0; it < NKI; ++it) {
        half8 anext[4], bnext[4];
        {   // prefetch it+1 (branchless; padded Bf + sf slack rows make it safe)
            const half8* bn = bfp + (it + 1) * (2 * 4 * 64);
            #pragma unroll
            for (int j = 0; j < 4; ++j) bnext[j] = bn[j * 64];
            #pragma unroll
            for (int i = 0; i < 4; ++i)
                anext[i] = *(const half8*)(sf + aoff + i * 16 * SF_STRIDE);
        }
        #pragma unroll
        for (int i = 0; i < 4; ++i)
            #pragma unroll
            for (int j = 0; j < 4; ++j)
                acc[i][j] = __builtin_amdgcn_mfma_f32_16x16x32_f16(acur[i], bcur[j], acc[i][j], 0, 0, 0);
        #pragma unroll
        for (int i = 0; i < 4; ++i) acur[i] = anext[i];
        #pragma unroll
        for (int j = 0; j < 4; ++j) bcur[j] = bnext[j];
        aoff += 32; c += 32;
        if (c >= 80) { c -= 80; aoff += 8; }
    }

    // ---- epilogue: bias + ReLU + mean-pool ----
    float bias[4];
    #pragma unroll
    for (int j = 0; j < 4; ++j) bias[j] = enc_b[h0 + wn + j * 16 + ml];

    #pragma unroll
    for (int i = 0; i < 4; ++i) {
        const int tg = t0 + wm + i * 16;
        const int w0  = wlo[i];
        const int w15 = whi[i];
        if (w0 == w15) {
            if (w0 >= 0) {
                const float inv = inv_cnt[bW + w0];
                const bool own_lo = (tg == 0) || (word_of[bT + tg - 1] != w0);
                const bool own_hi = (tg + 16 >= T_) || (word_of[bT + tg + 16] != w0);
                #pragma unroll
                for (int j = 0; j < 4; ++j) {
                    float s = 0.f;
                    #pragma unroll
                    for (int r = 0; r < 4; ++r) s += fmaxf(acc[i][j][r] + bias[j], 0.f);
                    s += __shfl_down(s, 32, 64);
                    s += __shfl_down(s, 16, 64);
                    if (q == 0) {
                        float val = s * inv;
                        float* dst = &wemb[(size_t)(bW + w0) * H_ + h0 + wn + j * 16 + ml];
                        if (own_lo && own_hi) *dst = val;       // sole owner
                        else atomicAdd(dst, val);
                    }
                }
            }
        } else {
            #pragma unroll
            for (int j = 0; j < 4; ++j) {
                #pragma unroll
                for (int r = 0; r < 4; ++r) {
                    int t = tg + q * 4 + r;
                    int w = word_of[bT + t];
                    if (w >= 0)
                        atomicAdd(&wemb[(size_t)(bW + w) * H_ + h0 + wn + j * 16 + ml],
                                  fmaxf(acc[i][j][r] + bias[j], 0.f) * inv_cnt[bW + w]);
                }
            }
        }
    }
}

// ---------------------------------------------------------------------------
// Decoder, single dispatch (unchanged from round 6)
// ---------------------------------------------------------------------------
__global__ __launch_bounds__(256) void dec_all(const float* __restrict__ wemb,
                                               const float* __restrict__ dec_w,
                                               const float* __restrict__ dec_b,
                                               float* __restrict__ out) {
    __shared__ float sdw[H_ * K_];       // 10.2 KB
    __shared__ float se[36][8];          // e rows, k-stride 8
    const int bid = blockIdx.x;          // b*4 + ch
    const int b = bid >> 2, ch = bid & 3;
    const int w0 = ch * 32;
    for (int idx = threadIdx.x; idx < H_ * K_; idx += 256) sdw[idx] = dec_w[idx];
    __syncthreads();
    const int wid = threadIdx.x >> 6, lane = threadIdx.x & 63;
    for (int row = wid; row < 36; row += 4) {
        int wq = w0 - 2 + row;
        float a[K_] = {};
        if (wq >= 0 && wq < W_) {
            const float* src = wemb + ((size_t)b * W_ + wq) * H_;
            #pragma unroll
            for (int r = 0; r < H_ / 64; ++r) {
                int h = r * 64 + lane;
                float v = src[h];
                #pragma unroll
                for (int k = 0; k < K_; ++k) a[k] += v * sdw[h * K_ + k];
            }
        }
        #pragma unroll
        for (int k = 0; k < K_; ++k) {
            #pragma unroll
            for (int off = 32; off > 0; off >>= 1) a[k] += __shfl_down(a[k], off, 64);
        }
        if (lane == 0) {
            #pragma unroll
            for (int k = 0; k < K_; ++k) se[row][k] = a[k];
        }
    }
    __syncthreads();
    if (threadIdx.x < 32) {
        int wl = threadIdx.x;
        float acc = dec_b[0];
        #pragma unroll
        for (int k = 0; k < K_; ++k) acc += se[wl + k][k];
        out[b * W_ + w0 + wl] = acc;
    }
}

// ---------------------------------------------------------------------------
extern "C" void kernel_launch(void* const* d_in, const int* in_sizes, int n_in,
                              void* d_out, int out_size, void* d_ws, size_t ws_size,
                              hipStream_t stream) {
    const float* feat    = (const float*)d_in[0];
    const int*   bounds  = (const int*)  d_in[1];
    const int*   lengths = (const int*)  d_in[2];
    const float* enc_w   = (const float*)d_in[3];
    const float* enc_b   = (const float*)d_in[4];
    const float* dec_w   = (const float*)d_in[5];
    const float* dec_b   = (const float*)d_in[6];
    float* out = (float*)d_out;

    char* p = (char*)d_ws;
    _Float16* featT = (_Float16*)p;  p += (size_t)B_ * T_ * C_ * 2;             // 10.49 MB
    _Float16* Bf    = (_Float16*)p;  p += (size_t)(BF_ELEMS + ITER_STRIDE) * 2; // 0.43 MB (+pad)
    int* word_of    = (int*)p;       p += (size_t)B_ * T_ * 4;                  // 0.26 MB
    float* inv_cnt  = (float*)p;     p += (size_t)B_ * W_ * 4;                  // 16 KB
    float* wemb     = (float*)p;                                                // 8.39 MB

    prep_all<<<RB_WZERO, 256, 0, stream>>>(feat, enc_w, bounds, lengths,
                                           featT, Bf, word_of, inv_cnt, wemb);
    gemm_enc<<<B_ * (T_ / TM) * (H_ / TN), 256, 0, stream>>>(
        featT, Bf, enc_b, word_of, inv_cnt, wemb);
    dec_all<<<B_ * 4, 256, 0, stream>>>(wemb, dec_w, dec_b, out);
}

// Round 8
// 126.607 us; speedup vs baseline: 1.1949x; 1.0245x over previous
//
#include <hip/hip_runtime.h>

#define B_ 32
#define C_ 80
#define T_ 2048
#define W_ 128
#define H_ 512
#define K_ 5

#define KTOT 400          // C_*K_
#define KPAD 416          // padded to 13*32
#define NKI  13           // K iterations of 32
#define TM   128
#define TN   128
#define SF_STRIDE 88      // f16 units
#define SF_ROWS   136     // 128 + 4 halo + 4 tail-slack (A-prefetch overrun safe)
#define ITER_STRIDE (2 * 4 * 64 * 8)               // Bf elems per K-iter per nt
#define BF_ELEMS  (4 * NKI * ITER_STRIDE)          // [nt][it][w2][j][lane][8] = 212992

// prep_all block-role boundaries
#define RB_FEAT   1024                             // feat transpose blocks
#define RB_BFRAG  (RB_FEAT + BF_ELEMS / 256)       // +832 = 1856
#define RB_WORDS  (RB_BFRAG + B_)                  // +32  = 1888
#define RB_WZERO  (RB_WORDS + 128)                 // +128 = 2016 (wemb zero)

typedef _Float16 half8 __attribute__((ext_vector_type(8)));
typedef float    f4v   __attribute__((ext_vector_type(4)));

// ---------------------------------------------------------------------------
// prep_all: one dispatch, four roles by blockIdx.x (unchanged)
// ---------------------------------------------------------------------------
__global__ __launch_bounds__(256) void prep_all(
    const float* __restrict__ feat, const float* __restrict__ enc_w,
    const int* __restrict__ bounds, const int* __restrict__ lengths,
    _Float16* __restrict__ featT, _Float16* __restrict__ Bf,
    int* __restrict__ word_of, float* __restrict__ inv_cnt,
    float* __restrict__ wemb)
{
    __shared__ _Float16 tile[64 * 80];
    const int bid = blockIdx.x;
    const int tid = threadIdx.x;

    if (bid < RB_FEAT) {
        const int b = bid >> 5, tc = bid & 31;
        const int t0 = tc * 64;
        for (int idx = tid; idx < 80 * 64; idx += 256) {
            int cc = idx >> 6, tt = idx & 63;                  // coalesced over tt
            float v = feat[((size_t)b * C_ + cc) * T_ + t0 + tt];
            tile[tt * 80 + cc] = (_Float16)v;
        }
        __syncthreads();
        for (int idx = tid; idx < 64 * 10; idx += 256) {
            int tt = idx / 10, g = idx % 10;                   // coalesced writes
            *(f4v*)(featT + ((size_t)b * T_ + t0 + tt) * C_ + g * 8) =
                *(const f4v*)(tile + tt * 80 + g * 8);
        }
    } else if (bid < RB_BFRAG) {
        int idx = (bid - RB_FEAT) * 256 + tid;                 // < BF_ELEMS exactly
        int e  = idx & 7;
        int l  = (idx >> 3) & 63;
        int j  = (idx >> 9) & 3;
        int w2 = (idx >> 11) & 1;
        int it = (idx >> 12) % NKI;
        int nt = idx / (NKI << 12);
        int h  = nt * 128 + w2 * 64 + j * 16 + (l & 15);
        int kc = it * 32 + (l >> 4) * 8 + e;
        float v = 0.f;
        if (kc < KTOT) v = enc_w[(h * C_ + kc % 80) * K_ + kc / 80];
        Bf[idx] = (_Float16)v;
    } else if (bid < RB_WORDS) {
        const int b = bid - RB_BFRAG;
        int* wob = word_of + b * T_;
        for (int t = tid; t < T_; t += 256) wob[t] = -1;
        __syncthreads();
        if (tid < W_) {
            const int len = lengths[b];
            int s = bounds[(b * 2 + 0) * W_ + tid];
            int e = bounds[(b * 2 + 1) * W_ + tid];
            s = max(s, 0); e = min(e, T_);
            bool valid = (tid < len) && (e > s);
            inv_cnt[b * W_ + tid] = valid ? 1.f / (float)(e - s) : 0.f;
            if (valid)
                for (int t = s; t < e; ++t) wob[t] = tid;      // disjoint words
        }
    } else {
        f4v* wz = (f4v*)wemb;
        int base = (bid - RB_WORDS) * 256 + tid;
        for (int i = base; i < (B_ * W_ * H_) / 4; i += 128 * 256) wz[i] = (f4v){};
    }
}

// ---------------------------------------------------------------------------
// Implicit-GEMM conv (f16 MFMA) + bias + ReLU + word mean-pool into wemb.
// Round-8: K-loop FULLY UNROLLED (rotation = SSA renaming, no movs; wrap
// arithmetic predicated per iter), B prefetch depth 2 (covers L2 latency),
// A prefetch depth 1 from LDS. Bf padded +2 iters for branchless prefetch.
// ---------------------------------------------------------------------------
__global__ __launch_bounds__(256, 3) void gemm_enc(
    const _Float16* __restrict__ featT,   // (B,T,C)
    const _Float16* __restrict__ Bf,      // wave-order fragments (padded +2 iters)
    const float*    __restrict__ enc_b,   // (H)
    const int*      __restrict__ word_of, // (B,T)
    const float*    __restrict__ inv_cnt, // (B,W)
    float*          __restrict__ wemb)    // (B,W,H) pre-zeroed
{
    __shared__ _Float16 sf[SF_ROWS * SF_STRIDE];   // 23.9 KB

    const int tid = threadIdx.x;
    const int bid = blockIdx.x;
    const int nt = bid & 3;          // nt in low bits: Bf slice L2 locality
    const int mt = (bid >> 2) & 15;
    const int b  = bid >> 6;
    const int t0 = mt * TM;
    const int h0 = nt * TN;

    // ---- stage A tile (rows tt: t = t0-2+tt, zero outside [0,T)) ----
    const _Float16* fb = featT + (size_t)b * T_ * C_;
    for (int idx = tid; idx < SF_ROWS * 10; idx += 256) {
        int tt = idx / 10, g = idx % 10;
        int t = t0 - 2 + tt;
        int tcl = min(max(t, 0), T_ - 1);
        f4v v = {};
        if (t >= 0 && t < T_) v = *(const f4v*)(fb + tcl * C_ + g * 8);
        *(f4v*)(sf + tt * SF_STRIDE + g * 8) = v;
    }

    const int lane = tid & 63;
    const int wid  = tid >> 6;
    const int wm = (wid >> 1) * 64;
    const int wn = (wid & 1) * 64;
    const int w2 = wid & 1;
    const int ml = lane & 15;
    const int q  = lane >> 4;

    // B fragment stream base; iter stride = 512 half8
    const half8* bfp = (const half8*)(Bf + (((nt * NKI) * 2 + w2) * 4 * 64 + lane) * 8);

    // ---- epilogue scalar prefetch (independent of K-loop) ----
    const int bT = b * T_;
    const int bW = b * W_;
    int wlo[4], whi[4];
    #pragma unroll
    for (int i = 0; i < 4; ++i) {
        const int tg = t0 + wm + i * 16;
        wlo[i] = word_of[bT + tg];
        whi[i] = word_of[bT + tg + 15];
    }

    f4v acc[4][4] = {};

    __syncthreads();   // sf ready; no more barriers below

    int c = q * 8;
    int aoff = (wm + ml) * SF_STRIDE + c;

    // preload: A(it0) from LDS; B(it0), B(it1) from global
    half8 acur[4], bcur[4], bnxt[4];
    #pragma unroll
    for (int i = 0; i < 4; ++i)
        acur[i] = *(const half8*)(sf + aoff + i * 16 * SF_STRIDE);
    #pragma unroll
    for (int j = 0; j < 4; ++j) bcur[j] = bfp[j * 64];
    #pragma unroll
    for (int j = 0; j < 4; ++j) bnxt[j] = bfp[512 + j * 64];
    aoff += 32; c += 32;
    if (c >= 80) { c -= 80; aoff += 8; }    // -> it=1 A address

    #pragma unroll
    for (int it = 0; it < NKI; ++it) {
        half8 anxt[4], bnn[4];
        // prefetch A(it+1) from LDS (slack rows make it=NKI safe)
        #pragma unroll
        for (int i = 0; i < 4; ++i)
            anxt[i] = *(const half8*)(sf + aoff + i * 16 * SF_STRIDE);
        // prefetch B(it+2) from global (Bf padded +2 iters)
        {
            const half8* bn = bfp + (it + 2) * 512;
            #pragma unroll
            for (int j = 0; j < 4; ++j) bnn[j] = bn[j * 64];
        }
        #pragma unroll
        for (int i = 0; i < 4; ++i)
            #pragma unroll
            for (int j = 0; j < 4; ++j)
                acc[i][j] = __builtin_amdgcn_mfma_f32_16x16x32_f16(acur[i], bcur[j], acc[i][j], 0, 0, 0);
        // rotations: pure renaming under full unroll
        #pragma unroll
        for (int i = 0; i < 4; ++i) acur[i] = anxt[i];
        #pragma unroll
        for (int j = 0; j < 4; ++j) { bcur[j] = bnxt[j]; bnxt[j] = bnn[j]; }
        aoff += 32; c += 32;
        if (c >= 80) { c -= 80; aoff += 8; }
    }

    // ---- epilogue: bias + ReLU + mean-pool ----
    float bias[4];
    #pragma unroll
    for (int j = 0; j < 4; ++j) bias[j] = enc_b[h0 + wn + j * 16 + ml];

    #pragma unroll
    for (int i = 0; i < 4; ++i) {
        const int tg = t0 + wm + i * 16;
        const int w0  = wlo[i];
        const int w15 = whi[i];
        if (w0 == w15) {
            if (w0 >= 0) {
                const float inv = inv_cnt[bW + w0];
                const bool own_lo = (tg == 0) || (word_of[bT + tg - 1] != w0);
                const bool own_hi = (tg + 16 >= T_) || (word_of[bT + tg + 16] != w0);
                #pragma unroll
                for (int j = 0; j < 4; ++j) {
                    float s = 0.f;
                    #pragma unroll
                    for (int r = 0; r < 4; ++r) s += fmaxf(acc[i][j][r] + bias[j], 0.f);
                    s += __shfl_down(s, 32, 64);
                    s += __shfl_down(s, 16, 64);
                    if (q == 0) {
                        float val = s * inv;
                        float* dst = &wemb[(size_t)(bW + w0) * H_ + h0 + wn + j * 16 + ml];
                        if (own_lo && own_hi) *dst = val;       // sole owner
                        else atomicAdd(dst, val);
                    }
                }
            }
        } else {
            #pragma unroll
            for (int j = 0; j < 4; ++j) {
                #pragma unroll
                for (int r = 0; r < 4; ++r) {
                    int t = tg + q * 4 + r;
                    int w = word_of[bT + t];
                    if (w >= 0)
                        atomicAdd(&wemb[(size_t)(bW + w) * H_ + h0 + wn + j * 16 + ml],
                                  fmaxf(acc[i][j][r] + bias[j], 0.f) * inv_cnt[bW + w]);
                }
            }
        }
    }
}

// ---------------------------------------------------------------------------
// Decoder, single dispatch (unchanged)
// ---------------------------------------------------------------------------
__global__ __launch_bounds__(256) void dec_all(const float* __restrict__ wemb,
                                               const float* __restrict__ dec_w,
                                               const float* __restrict__ dec_b,
                                               float* __restrict__ out) {
    __shared__ float sdw[H_ * K_];       // 10.2 KB
    __shared__ float se[36][8];          // e rows, k-stride 8
    const int bid = blockIdx.x;          // b*4 + ch
    const int b = bid >> 2, ch = bid & 3;
    const int w0 = ch * 32;
    for (int idx = threadIdx.x; idx < H_ * K_; idx += 256) sdw[idx] = dec_w[idx];
    __syncthreads();
    const int wid = threadIdx.x >> 6, lane = threadIdx.x & 63;
    for (int row = wid; row < 36; row += 4) {
        int wq = w0 - 2 + row;
        float a[K_] = {};
        if (wq >= 0 && wq < W_) {
            const float* src = wemb + ((size_t)b * W_ + wq) * H_;
            #pragma unroll
            for (int r = 0; r < H_ / 64; ++r) {
                int h = r * 64 + lane;
                float v = src[h];
                #pragma unroll
                for (int k = 0; k < K_; ++k) a[k] += v * sdw[h * K_ + k];
            }
        }
        #pragma unroll
        for (int k = 0; k < K_; ++k) {
            #pragma unroll
            for (int off = 32; off > 0; off >>= 1) a[k] += __shfl_down(a[k], off, 64);
        }
        if (lane == 0) {
            #pragma unroll
            for (int k = 0; k < K_; ++k) se[row][k] = a[k];
        }
    }
    __syncthreads();
    if (threadIdx.x < 32) {
        int wl = threadIdx.x;
        float acc = dec_b[0];
        #pragma unroll
        for (int k = 0; k < K_; ++k) acc += se[wl + k][k];
        out[b * W_ + w0 + wl] = acc;
    }
}

// ---------------------------------------------------------------------------
extern "C" void kernel_launch(void* const* d_in, const int* in_sizes, int n_in,
                              void* d_out, int out_size, void* d_ws, size_t ws_size,
                              hipStream_t stream) {
    const float* feat    = (const float*)d_in[0];
    const int*   bounds  = (const int*)  d_in[1];
    const int*   lengths = (const int*)  d_in[2];
    const float* enc_w   = (const float*)d_in[3];
    const float* enc_b   = (const float*)d_in[4];
    const float* dec_w   = (const float*)d_in[5];
    const float* dec_b   = (const float*)d_in[6];
    float* out = (float*)d_out;

    char* p = (char*)d_ws;
    _Float16* featT = (_Float16*)p;  p += (size_t)B_ * T_ * C_ * 2;                 // 10.49 MB
    _Float16* Bf    = (_Float16*)p;  p += (size_t)(BF_ELEMS + 2 * ITER_STRIDE) * 2; // 0.44 MB (+2-iter pad)
    int* word_of    = (int*)p;       p += (size_t)B_ * T_ * 4;                      // 0.26 MB
    float* inv_cnt  = (float*)p;     p += (size_t)B_ * W_ * 4;                      // 16 KB
    float* wemb     = (float*)p;                                                    // 8.39 MB

    prep_all<<<RB_WZERO, 256, 0, stream>>>(feat, enc_w, bounds, lengths,
                                           featT, Bf, word_of, inv_cnt, wemb);
    gemm_enc<<<B_ * (T_ / TM) * (H_ / TN), 256, 0, stream>>>(
        featT, Bf, enc_b, word_of, inv_cnt, wemb);
    dec_all<<<B_ * 4, 256, 0, stream>>>(wemb, dec_w, dec_b, out);
}